// Round 2
// baseline (673.814 us; speedup 1.0000x reference)
//
#include <hip/hip_runtime.h>
#include <stdint.h>

// ---------------------------------------------------------------------------
// ThirdOrderAttention: B=1, N=256, C=512, H=8, D=64
// Flash attention over virtual L=65536 KV (K'=kj*kk, V'=vj*vk), bf16 MFMA,
// no max-subtraction (scores tiny). R2: atomic-free partial slabs + LDS
// cross-wave reduce; grid (8h,4ic,32jc)=1024 blocks for 16 waves/CU.
// ---------------------------------------------------------------------------

typedef __attribute__((ext_vector_type(4))) float f32x4;
typedef __attribute__((ext_vector_type(4))) short s16x4;
typedef __attribute__((ext_vector_type(8))) short s16x8;

#define H_ 8
#define N_ 256
#define D_ 64
#define C_ 512
#define NC5 2560
#define SCALE_LOG2E 0.1803368801111204f  // 0.125 * log2(e): P = exp2(S')

// ----- bf16 helpers --------------------------------------------------------
__device__ __forceinline__ unsigned short f2bf_rne(float x) {
  union { float f; unsigned u; } a; a.f = x;
  unsigned r = a.u + 0x7fffu + ((a.u >> 16) & 1u);
  return (unsigned short)(r >> 16);
}

__device__ __forceinline__ unsigned pk_bf16(float a, float b) {
#if __has_builtin(__builtin_amdgcn_cvt_pk_bf16_f32)
  typedef __attribute__((ext_vector_type(2))) __bf16 bf16x2;
  union { bf16x2 v; unsigned u; } u;
  u.v = __builtin_amdgcn_cvt_pk_bf16_f32(a, b);
  return u.u;
#else
  return (unsigned)f2bf_rne(a) | ((unsigned)f2bf_rne(b) << 16);
#endif
}

// ----- MFMA wrappers -------------------------------------------------------
__device__ __forceinline__ f32x4 mfma32(s16x8 a, s16x8 b, f32x4 c) {
  return __builtin_amdgcn_mfma_f32_16x16x32_bf16(a, b, c, 0, 0, 0);
}

__device__ __forceinline__ f32x4 mfma16(s16x4 a, s16x4 b, f32x4 c) {
#if __has_builtin(__builtin_amdgcn_mfma_f32_16x16x16bf16_1k)
  return __builtin_amdgcn_mfma_f32_16x16x16bf16_1k(a, b, c, 0, 0, 0);
#else
  asm volatile("s_nop 1\n\t"
               "v_mfma_f32_16x16x16_bf16 %0, %1, %2, %0\n\t"
               "s_nop 7\n\t"
               "s_nop 2"
               : "+v"(c) : "v"(a), "v"(b));
  return c;
#endif
}

// ---------------------------------------------------------------------------
// Kernel 1: projection GEMM  p = x[256,512] @ W_att[512,2560] + b_att
// BM=64, BN=64, BK=16; 256 threads; micro-tile 4x4. Grid (40, 4).
// Epilogue routes columns into per-head q (bf16, pre-scaled), kj, kk, vj, vkT.
// ---------------------------------------------------------------------------
__global__ __launch_bounds__(256) void proj_kernel(
    const float* __restrict__ x, const float* __restrict__ W,
    const float* __restrict__ b,
    unsigned short* __restrict__ qB, float* __restrict__ kj,
    float* __restrict__ kk, float* __restrict__ vj, float* __restrict__ vkT) {
  __shared__ float As[16][65];
  __shared__ float Bs[16][68];
  const int bx = blockIdx.x;  // 40 col tiles of 64
  const int by = blockIdx.y;  // 4 row tiles of 64
  const int tid = threadIdx.x;
  const int tr = (tid >> 4) * 4;  // row 0..60
  const int tc = (tid & 15) * 4;  // col 0..60
  float accv[4][4] = {};

  for (int k0 = 0; k0 < C_; k0 += 16) {
#pragma unroll
    for (int t = 0; t < 4; ++t) {
      int e = tid + t * 256;
      int r = e >> 4, kq = e & 15;
      As[kq][r] = x[(by * 64 + r) * C_ + k0 + kq];
    }
    {
      int br = tid >> 4, bc = (tid & 15) * 4;
      *(f32x4*)&Bs[br][bc] = *(const f32x4*)&W[(k0 + br) * NC5 + bx * 64 + bc];
    }
    __syncthreads();
#pragma unroll
    for (int kq = 0; kq < 16; ++kq) {
      float a0 = As[kq][tr + 0], a1 = As[kq][tr + 1];
      float a2 = As[kq][tr + 2], a3 = As[kq][tr + 3];
      float b0 = Bs[kq][tc + 0], b1 = Bs[kq][tc + 1];
      float b2 = Bs[kq][tc + 2], b3 = Bs[kq][tc + 3];
      accv[0][0] += a0 * b0; accv[0][1] += a0 * b1; accv[0][2] += a0 * b2; accv[0][3] += a0 * b3;
      accv[1][0] += a1 * b0; accv[1][1] += a1 * b1; accv[1][2] += a1 * b2; accv[1][3] += a1 * b3;
      accv[2][0] += a2 * b0; accv[2][1] += a2 * b1; accv[2][2] += a2 * b2; accv[2][3] += a2 * b3;
      accv[3][0] += a3 * b0; accv[3][1] += a3 * b1; accv[3][2] += a3 * b2; accv[3][3] += a3 * b3;
    }
    __syncthreads();
  }

#pragma unroll
  for (int rr = 0; rr < 4; ++rr)
#pragma unroll
    for (int cc = 0; cc < 4; ++cc) {
      int i = by * 64 + tr + rr;
      int col = bx * 64 + tc + cc;
      float v = accv[rr][cc] + b[col];
      int h = col / 320;
      int rm = col % 320;
      int part = rm >> 6;
      int d = rm & 63;
      int idx = (h * N_ + i) * D_ + d;
      if (part == 0)      qB[idx] = f2bf_rne(v * SCALE_LOG2E);
      else if (part == 1) kj[idx] = v;
      else if (part == 2) kk[idx] = v;
      else if (part == 3) vj[idx] = v;
      else                vkT[(h * D_ + d) * N_ + i] = v;
    }
}

// ---------------------------------------------------------------------------
// Kernel 2: fused third-order flash attention (atomic-free).
// Grid (8 h, 4 i-chunks of 64, 32 j-chunks of 8). Block 256 = 4 waves;
// each wave owns 2 j's, all 64 i of the chunk, all 256 k.
// Per (j, k0) subtile of 64 t = (j,k):
//   S^T[t,i] = E[t,:] . Q[i,:]   via mfma 16x16x32 (A=E built in-regs)
//   P = exp2(S'); C-layout of S^T IS the B-layout of mfma 16x16x16 -> PV gemm
//   Y^T[d,i] += F[d,t-slice] @ P^T  via mfma 16x16x16 (A=F built in-regs)
// Epilogue: 2-step LDS tree reduce across the 4 waves (j partials), then one
// non-atomic 16KB fp32 slab write per block.
// ---------------------------------------------------------------------------
__global__ __launch_bounds__(256, 4) void flash3_kernel(
    const unsigned short* __restrict__ qB,  // [H][N][D] bf16 (pre-scaled)
    const float* __restrict__ kjF,          // [H][N][D]
    const float* __restrict__ kkF,          // [H][N][D]
    const float* __restrict__ vjF,          // [H][N][D]
    const float* __restrict__ vkT,          // [H][D][N]
    float* __restrict__ slab,               // [H][32][4][64][64]
    float* __restrict__ lslab) {            // [H][32][256]
  const int h = blockIdx.x;
  const int ic = blockIdx.y;  // i chunk of 64
  const int jc = blockIdx.z;  // j chunk of 8
  const int wave = threadIdx.x >> 6;
  const int lane = threadIdx.x & 63;
  const int q = lane >> 4;
  const int c = lane & 15;
  const int i0 = ic * 64;

  const unsigned short* qh = qB + h * (N_ * D_);
  const float* kjh = kjF + h * (N_ * D_);
  const float* kkh = kkF + h * (N_ * D_);
  const float* vjh = vjF + h * (N_ * D_);
  const float* vkh = vkT + h * (D_ * N_);

  // Q B-fragments: B[k=d=q*8+j'][n=i=lane&15], per 32-d step
  s16x8 qf[4][2];
#pragma unroll
  for (int nb = 0; nb < 4; ++nb)
#pragma unroll
    for (int ks = 0; ks < 2; ++ks)
      qf[nb][ks] =
          *(const s16x8*)(qh + (i0 + nb * 16 + c) * D_ + ks * 32 + q * 8);

  f32x4 acc[4][4];  // Y^T tiles: [mb over d][nb over i]
#pragma unroll
  for (int mb = 0; mb < 4; ++mb)
#pragma unroll
    for (int nb = 0; nb < 4; ++nb) acc[mb][nb] = (f32x4){0.f, 0.f, 0.f, 0.f};
  float lac[4] = {0.f, 0.f, 0.f, 0.f};

  for (int jj = 0; jj < 2; ++jj) {
    const int j = jc * 8 + wave * 2 + jj;
    const f32x4 kj0a = *(const f32x4*)(kjh + j * D_ + q * 8);
    const f32x4 kj0b = *(const f32x4*)(kjh + j * D_ + q * 8 + 4);
    const f32x4 kj1a = *(const f32x4*)(kjh + j * D_ + 32 + q * 8);
    const f32x4 kj1b = *(const f32x4*)(kjh + j * D_ + 32 + q * 8 + 4);
    float vjv[4];
#pragma unroll
    for (int mb = 0; mb < 4; ++mb) vjv[mb] = vjh[j * D_ + mb * 16 + c];

    for (int k0 = 0; k0 < N_; k0 += 64) {
      unsigned pb[4][4][2];  // P bf16 pairs: [t-slice][nb][dword]
#pragma unroll
      for (int mb = 0; mb < 4; ++mb) {
        // E A-frag: m = t = k0+mb*16+c ; k = d = ks*32 + q*8 + 0..7
        const int trow = k0 + mb * 16 + c;
        const float* kkp = kkh + trow * D_;
        f32x4 k0a = *(const f32x4*)(kkp + q * 8);
        f32x4 k0b = *(const f32x4*)(kkp + q * 8 + 4);
        f32x4 k1a = *(const f32x4*)(kkp + 32 + q * 8);
        f32x4 k1b = *(const f32x4*)(kkp + 32 + q * 8 + 4);
        union { unsigned u[4]; s16x8 v; } ea0, ea1;
        ea0.u[0] = pk_bf16(k0a.x * kj0a.x, k0a.y * kj0a.y);
        ea0.u[1] = pk_bf16(k0a.z * kj0a.z, k0a.w * kj0a.w);
        ea0.u[2] = pk_bf16(k0b.x * kj0b.x, k0b.y * kj0b.y);
        ea0.u[3] = pk_bf16(k0b.z * kj0b.z, k0b.w * kj0b.w);
        ea1.u[0] = pk_bf16(k1a.x * kj1a.x, k1a.y * kj1a.y);
        ea1.u[1] = pk_bf16(k1a.z * kj1a.z, k1a.w * kj1a.w);
        ea1.u[2] = pk_bf16(k1b.x * kj1b.x, k1b.y * kj1b.y);
        ea1.u[3] = pk_bf16(k1b.z * kj1b.z, k1b.w * kj1b.w);

        f32x4 st[4];
#pragma unroll
        for (int nb = 0; nb < 4; ++nb) {
          f32x4 z = (f32x4){0.f, 0.f, 0.f, 0.f};
          z = mfma32(ea0.v, qf[nb][0], z);
          z = mfma32(ea1.v, qf[nb][1], z);
          st[nb] = z;
        }
#pragma unroll
        for (int nb = 0; nb < 4; ++nb) {
          float p0 = __builtin_exp2f(st[nb].x);
          float p1 = __builtin_exp2f(st[nb].y);
          float p2 = __builtin_exp2f(st[nb].z);
          float p3 = __builtin_exp2f(st[nb].w);
          lac[nb] += (p0 + p1) + (p2 + p3);
          pb[mb][nb][0] = pk_bf16(p0, p1);
          pb[mb][nb][1] = pk_bf16(p2, p3);
        }
      }
      // PV gemm: Y^T[d,i] += F[d, t16] @ P^T[t16, i], K=16 per step
#pragma unroll
      for (int kt = 0; kt < 4; ++kt) {
        s16x4 ft[4];
#pragma unroll
        for (int mb = 0; mb < 4; ++mb) {
          // F A-frag: m = d = mb*16+c ; k = t = kt*16 + q*4 + 0..3
          const float* vp = vkh + (mb * 16 + c) * N_ + k0 + kt * 16 + q * 4;
          f32x4 v = *(const f32x4*)vp;
          float s = vjv[mb];
          union { unsigned u[2]; s16x4 v4; } t;
          t.u[0] = pk_bf16(v.x * s, v.y * s);
          t.u[1] = pk_bf16(v.z * s, v.w * s);
          ft[mb] = t.v4;
        }
#pragma unroll
        for (int mb = 0; mb < 4; ++mb)
#pragma unroll
          for (int nb = 0; nb < 4; ++nb) {
            union { unsigned u[2]; s16x4 v4; } p;
            p.u[0] = pb[kt][nb][0];
            p.u[1] = pb[kt][nb][1];
            acc[mb][nb] = mfma16(ft[mb], p.v4, acc[mb][nb]);
          }
      }
    }
  }

  // ---- epilogue: cross-wave tree reduce (waves hold different j partials) --
  __shared__ float red[2][4096];   // 32 KB
  __shared__ float lredA[2][64];
  __shared__ float lredB[64];

  float lv[4];
#pragma unroll
  for (int nb = 0; nb < 4; ++nb) {
    float v = lac[nb];
    v += __shfl_xor(v, 16);
    v += __shfl_xor(v, 32);
    lv[nb] = v;  // valid at q==0 lanes
  }

  if (wave >= 2) {
    float* dst = red[wave - 2];
#pragma unroll
    for (int mb = 0; mb < 4; ++mb)
#pragma unroll
      for (int nb = 0; nb < 4; ++nb)
        *(f32x4*)&dst[(nb * 16 + c) * 64 + mb * 16 + q * 4] = acc[mb][nb];
    if (q == 0)
#pragma unroll
      for (int nb = 0; nb < 4; ++nb) lredA[wave - 2][nb * 16 + c] = lv[nb];
  }
  __syncthreads();
  if (wave < 2) {
    const float* src = red[wave];
#pragma unroll
    for (int mb = 0; mb < 4; ++mb)
#pragma unroll
      for (int nb = 0; nb < 4; ++nb)
        acc[mb][nb] += *(const f32x4*)&src[(nb * 16 + c) * 64 + mb * 16 + q * 4];
    if (q == 0)
#pragma unroll
      for (int nb = 0; nb < 4; ++nb) lv[nb] += lredA[wave][nb * 16 + c];
  }
  __syncthreads();
  if (wave == 1) {
#pragma unroll
    for (int mb = 0; mb < 4; ++mb)
#pragma unroll
      for (int nb = 0; nb < 4; ++nb)
        *(f32x4*)&red[0][(nb * 16 + c) * 64 + mb * 16 + q * 4] = acc[mb][nb];
    if (q == 0)
#pragma unroll
      for (int nb = 0; nb < 4; ++nb) lredB[nb * 16 + c] = lv[nb];
  }
  __syncthreads();
  if (wave == 0) {
    float* out = slab + ((h * 32 + jc) * 4 + ic) * 4096;
#pragma unroll
    for (int mb = 0; mb < 4; ++mb)
#pragma unroll
      for (int nb = 0; nb < 4; ++nb) {
        f32x4 v = acc[mb][nb] +
                  *(const f32x4*)&red[0][(nb * 16 + c) * 64 + mb * 16 + q * 4];
        *(f32x4*)(out + (nb * 16 + c) * 64 + mb * 16 + q * 4) = v;
      }
    if (q == 0)
#pragma unroll
      for (int nb = 0; nb < 4; ++nb)
        lslab[(h * 32 + jc) * 256 + ic * 64 + nb * 16 + c] =
            lv[nb] + lredB[nb * 16 + c];
  }
}

// ---------------------------------------------------------------------------
// Kernel 3: reduce 32 j-chunk partials, normalize, head re-interleave.
// yn[i][h*64+d] = (sum_jc slab) / (sum_jc lslab)
// ---------------------------------------------------------------------------
__global__ __launch_bounds__(256) void reduce_kernel(
    const float* __restrict__ slab, const float* __restrict__ lslab,
    float* __restrict__ yn) {
  int idx = blockIdx.x * 256 + threadIdx.x;  // 131072 = 8h*4ic*64il*64d
  int h = idx >> 14;
  int r = idx & 16383;
  int ic = r >> 12;
  int il = (r >> 6) & 63;
  int d = r & 63;
  float s = 0.f, l = 0.f;
#pragma unroll 4
  for (int jc = 0; jc < 32; ++jc) {
    s += slab[(((h * 32 + jc) * 4 + ic) << 12) + il * 64 + d];
    l += lslab[(h * 32 + jc) * 256 + ic * 64 + il];
  }
  int i = ic * 64 + il;
  yn[i * C_ + h * 64 + d] = s / l;
}

// ---------------------------------------------------------------------------
// Kernel 4: out = yn[256,512] @ W_out[512,512] + b_out   (fp32, grid (8,8))
// ---------------------------------------------------------------------------
__global__ __launch_bounds__(256) void out_gemm(
    const float* __restrict__ A, const float* __restrict__ W,
    const float* __restrict__ b, float* __restrict__ out) {
  __shared__ float As[16][33];
  __shared__ float Bs[16][68];
  const int bx = blockIdx.x;  // 8 col tiles of 64
  const int by = blockIdx.y;  // 8 row tiles of 32
  const int tid = threadIdx.x;
  const int tr = (tid >> 5) * 4;
  const int tc = (tid & 31) * 2;
  float accv[4][2] = {};

  for (int k0 = 0; k0 < C_; k0 += 16) {
#pragma unroll
    for (int t = 0; t < 2; ++t) {
      int e = tid + t * 256;
      int r = e >> 4, kq = e & 15;
      As[kq][r] = A[(by * 32 + r) * C_ + k0 + kq];
    }
    {
      int br = tid >> 4, bc = (tid & 15) * 4;
      *(f32x4*)&Bs[br][bc] = *(const f32x4*)&W[(k0 + br) * C_ + bx * 64 + bc];
    }
    __syncthreads();
#pragma unroll
    for (int kq = 0; kq < 16; ++kq) {
      float a0 = As[kq][tr + 0], a1 = As[kq][tr + 1];
      float a2 = As[kq][tr + 2], a3 = As[kq][tr + 3];
      float b0 = Bs[kq][tc + 0], b1 = Bs[kq][tc + 1];
      accv[0][0] += a0 * b0; accv[0][1] += a0 * b1;
      accv[1][0] += a1 * b0; accv[1][1] += a1 * b1;
      accv[2][0] += a2 * b0; accv[2][1] += a2 * b1;
      accv[3][0] += a3 * b0; accv[3][1] += a3 * b1;
    }
    __syncthreads();
  }
#pragma unroll
  for (int rr = 0; rr < 4; ++rr)
#pragma unroll
    for (int cc = 0; cc < 2; ++cc) {
      int i = by * 32 + tr + rr;
      int col = bx * 64 + tc + cc;
      out[i * C_ + col] = accv[rr][cc] + b[col];
    }
}

// ---------------------------------------------------------------------------
extern "C" void kernel_launch(void* const* d_in, const int* in_sizes, int n_in,
                              void* d_out, int out_size, void* d_ws,
                              size_t ws_size, hipStream_t stream) {
  const float* x     = (const float*)d_in[0];
  const float* W_att = (const float*)d_in[1];
  const float* b_att = (const float*)d_in[2];
  const float* W_out = (const float*)d_in[3];
  const float* b_out = (const float*)d_in[4];

  char* ws = (char*)d_ws;
  float* slab           = (float*)(ws + 0);         // 16777216 B
  float* lslab          = (float*)(ws + 16777216);  //   262144 B
  unsigned short* qB    = (unsigned short*)(ws + 17039360);  // 262144 B
  float* kj             = (float*)(ws + 17301504);  // 524288 B
  float* kk             = (float*)(ws + 17825792);  // 524288 B
  float* vj             = (float*)(ws + 18350080);  // 524288 B
  float* vkT            = (float*)(ws + 18874368);  // 524288 B
  float* yn             = (float*)(ws + 19398656);  // 524288 B

  proj_kernel<<<dim3(40, 4), 256, 0, stream>>>(x, W_att, b_att, qB, kj, kk, vj,
                                               vkT);
  flash3_kernel<<<dim3(8, 4, 32), 256, 0, stream>>>(qB, kj, kk, vj, vkT, slab,
                                                    lslab);
  reduce_kernel<<<dim3(512), 256, 0, stream>>>(slab, lslab, yn);
  out_gemm<<<dim3(8, 8), 256, 0, stream>>>(yn, W_out, b_out, (float*)d_out);
}

// Round 3
// 254.114 us; speedup vs baseline: 2.6516x; 2.6516x over previous
//
#include <hip/hip_runtime.h>
#include <stdint.h>

// ---------------------------------------------------------------------------
// ThirdOrderAttention: B=1, N=256, C=512, H=8, D=64
// Flash attention over virtual L=65536 KV (K'=kj*kk, V'=vj*vk), bf16 MFMA.
// R3: launch_bounds(256,2) (R2's (256,4) caused catastrophic spills);
// kj factored into Q (q~ = bf16(qS*kj), A-operand = pre-cast bf16 kk);
// per-slice S->PV interleave (pb 32->8 regs); padded epilogue LDS.
// ---------------------------------------------------------------------------

typedef __attribute__((ext_vector_type(4))) float f32x4;
typedef __attribute__((ext_vector_type(4))) short s16x4;
typedef __attribute__((ext_vector_type(8))) short s16x8;

#define H_ 8
#define N_ 256
#define D_ 64
#define C_ 512
#define NC5 2560
#define SCALE_LOG2E 0.1803368801111204f  // 0.125 * log2(e): P = exp2(S')

// ----- bf16 helpers --------------------------------------------------------
__device__ __forceinline__ unsigned short f2bf_rne(float x) {
  union { float f; unsigned u; } a; a.f = x;
  unsigned r = a.u + 0x7fffu + ((a.u >> 16) & 1u);
  return (unsigned short)(r >> 16);
}

__device__ __forceinline__ unsigned pk_bf16(float a, float b) {
#if __has_builtin(__builtin_amdgcn_cvt_pk_bf16_f32)
  typedef __attribute__((ext_vector_type(2))) __bf16 bf16x2;
  union { bf16x2 v; unsigned u; } u;
  u.v = __builtin_amdgcn_cvt_pk_bf16_f32(a, b);
  return u.u;
#else
  return (unsigned)f2bf_rne(a) | ((unsigned)f2bf_rne(b) << 16);
#endif
}

// ----- MFMA wrappers -------------------------------------------------------
__device__ __forceinline__ f32x4 mfma32(s16x8 a, s16x8 b, f32x4 c) {
  return __builtin_amdgcn_mfma_f32_16x16x32_bf16(a, b, c, 0, 0, 0);
}

__device__ __forceinline__ f32x4 mfma16(s16x4 a, s16x4 b, f32x4 c) {
#if __has_builtin(__builtin_amdgcn_mfma_f32_16x16x16bf16_1k)
  return __builtin_amdgcn_mfma_f32_16x16x16bf16_1k(a, b, c, 0, 0, 0);
#else
  asm volatile("s_nop 1\n\t"
               "v_mfma_f32_16x16x16_bf16 %0, %1, %2, %0\n\t"
               "s_nop 7\n\t"
               "s_nop 2"
               : "+v"(c) : "v"(a), "v"(b));
  return c;
#endif
}

// ---------------------------------------------------------------------------
// Kernel 1: projection GEMM  p = x[256,512] @ W_att[512,2560] + b_att
// BM=64, BN=64, BK=16; 256 threads; micro-tile 4x4. Grid (40, 4).
// Epilogue: qS f32 (pre-scaled), kj f32, kk bf16, vj f32, vkT f32.
// ---------------------------------------------------------------------------
__global__ __launch_bounds__(256) void proj_kernel(
    const float* __restrict__ x, const float* __restrict__ W,
    const float* __restrict__ b,
    float* __restrict__ qS, float* __restrict__ kj,
    unsigned short* __restrict__ kkB, float* __restrict__ vj,
    float* __restrict__ vkT) {
  __shared__ float As[16][65];
  __shared__ float Bs[16][68];
  const int bx = blockIdx.x;  // 40 col tiles of 64
  const int by = blockIdx.y;  // 4 row tiles of 64
  const int tid = threadIdx.x;
  const int tr = (tid >> 4) * 4;
  const int tc = (tid & 15) * 4;
  float accv[4][4] = {};

  for (int k0 = 0; k0 < C_; k0 += 16) {
#pragma unroll
    for (int t = 0; t < 4; ++t) {
      int e = tid + t * 256;
      int r = e >> 4, kq = e & 15;
      As[kq][r] = x[(by * 64 + r) * C_ + k0 + kq];
    }
    {
      int br = tid >> 4, bc = (tid & 15) * 4;
      *(f32x4*)&Bs[br][bc] = *(const f32x4*)&W[(k0 + br) * NC5 + bx * 64 + bc];
    }
    __syncthreads();
#pragma unroll
    for (int kq = 0; kq < 16; ++kq) {
      float a0 = As[kq][tr + 0], a1 = As[kq][tr + 1];
      float a2 = As[kq][tr + 2], a3 = As[kq][tr + 3];
      float b0 = Bs[kq][tc + 0], b1 = Bs[kq][tc + 1];
      float b2 = Bs[kq][tc + 2], b3 = Bs[kq][tc + 3];
      accv[0][0] += a0 * b0; accv[0][1] += a0 * b1; accv[0][2] += a0 * b2; accv[0][3] += a0 * b3;
      accv[1][0] += a1 * b0; accv[1][1] += a1 * b1; accv[1][2] += a1 * b2; accv[1][3] += a1 * b3;
      accv[2][0] += a2 * b0; accv[2][1] += a2 * b1; accv[2][2] += a2 * b2; accv[2][3] += a2 * b3;
      accv[3][0] += a3 * b0; accv[3][1] += a3 * b1; accv[3][2] += a3 * b2; accv[3][3] += a3 * b3;
    }
    __syncthreads();
  }

#pragma unroll
  for (int rr = 0; rr < 4; ++rr)
#pragma unroll
    for (int cc = 0; cc < 4; ++cc) {
      int i = by * 64 + tr + rr;
      int col = bx * 64 + tc + cc;
      float v = accv[rr][cc] + b[col];
      int h = col / 320;
      int rm = col % 320;
      int part = rm >> 6;
      int d = rm & 63;
      int idx = (h * N_ + i) * D_ + d;
      if (part == 0)      qS[idx] = v * SCALE_LOG2E;
      else if (part == 1) kj[idx] = v;
      else if (part == 2) kkB[idx] = f2bf_rne(v);
      else if (part == 3) vj[idx] = v;
      else                vkT[(h * D_ + d) * N_ + i] = v;
    }
}

// ---------------------------------------------------------------------------
// Kernel 2: fused third-order flash attention (atomic-free).
// Grid (8 h, 4 ic of 64 i, 32 jc of 8 j). Block 256 = 4 waves; each wave owns
// 2 j's, 64 i, all 256 k. Per (j, k0-tile of 64):
//   per 16-t slice mb: S^T = kk_bf16 . q~   (q~ = bf16(qS * kj), per-j)
//   P = exp2(S'); S^T C-layout == mfma16 B-layout -> immediate PV slice:
//   Y^T[d,i] += F[d,t16] @ P^T  (F = bf16(vj*vkT) built in-regs)
// Epilogue: LDS tree reduce over 4 waves, one 16 KB slab write per block.
// ---------------------------------------------------------------------------
__global__ __launch_bounds__(256, 2) void flash3_kernel(
    const float* __restrict__ qS,           // [H][N][D] f32, pre-scaled
    const float* __restrict__ kjF,          // [H][N][D] f32
    const unsigned short* __restrict__ kkB, // [H][N][D] bf16
    const float* __restrict__ vjF,          // [H][N][D] f32
    const float* __restrict__ vkT,          // [H][D][N] f32
    float* __restrict__ slab,               // [H][32][4][64][64]
    float* __restrict__ lslab) {            // [H][32][256]
  const int h = blockIdx.x;
  const int ic = blockIdx.y;
  const int jc = blockIdx.z;
  const int wave = threadIdx.x >> 6;
  const int lane = threadIdx.x & 63;
  const int q = lane >> 4;
  const int c = lane & 15;
  const int i0 = ic * 64;

  const float* qh = qS + h * (N_ * D_);
  const float* kjh = kjF + h * (N_ * D_);
  const unsigned short* kkh = kkB + h * (N_ * D_);
  const float* vjh = vjF + h * (N_ * D_);
  const float* vkh = vkT + h * (D_ * N_);

  f32x4 acc[4][4];  // Y^T tiles: [mb_d][nb over i]
#pragma unroll
  for (int mb = 0; mb < 4; ++mb)
#pragma unroll
    for (int nb = 0; nb < 4; ++nb) acc[mb][nb] = (f32x4){0.f, 0.f, 0.f, 0.f};
  float lac[4] = {0.f, 0.f, 0.f, 0.f};

  for (int jj = 0; jj < 2; ++jj) {
    const int j = jc * 8 + wave * 2 + jj;
    const f32x4 kj0a = *(const f32x4*)(kjh + j * D_ + q * 8);
    const f32x4 kj0b = *(const f32x4*)(kjh + j * D_ + q * 8 + 4);
    const f32x4 kj1a = *(const f32x4*)(kjh + j * D_ + 32 + q * 8);
    const f32x4 kj1b = *(const f32x4*)(kjh + j * D_ + 32 + q * 8 + 4);
    float vjv[4];
#pragma unroll
    for (int mb = 0; mb < 4; ++mb) vjv[mb] = vjh[j * D_ + mb * 16 + c];

    // q~ B-fragments: B[k=d][n=i], q~ = bf16(qS * kj)
    s16x8 qf[4][2];
#pragma unroll
    for (int nb = 0; nb < 4; ++nb) {
      const float* qp = qh + (i0 + nb * 16 + c) * D_;
      f32x4 a0 = *(const f32x4*)(qp + q * 8);
      f32x4 a1 = *(const f32x4*)(qp + q * 8 + 4);
      f32x4 b0 = *(const f32x4*)(qp + 32 + q * 8);
      f32x4 b1 = *(const f32x4*)(qp + 32 + q * 8 + 4);
      union { unsigned u[4]; s16x8 v; } t0, t1;
      t0.u[0] = pk_bf16(a0.x * kj0a.x, a0.y * kj0a.y);
      t0.u[1] = pk_bf16(a0.z * kj0a.z, a0.w * kj0a.w);
      t0.u[2] = pk_bf16(a1.x * kj0b.x, a1.y * kj0b.y);
      t0.u[3] = pk_bf16(a1.z * kj0b.z, a1.w * kj0b.w);
      t1.u[0] = pk_bf16(b0.x * kj1a.x, b0.y * kj1a.y);
      t1.u[1] = pk_bf16(b0.z * kj1a.z, b0.w * kj1a.w);
      t1.u[2] = pk_bf16(b1.x * kj1b.x, b1.y * kj1b.y);
      t1.u[3] = pk_bf16(b1.z * kj1b.z, b1.w * kj1b.w);
      qf[nb][0] = t0.v;
      qf[nb][1] = t1.v;
    }

    for (int k0 = 0; k0 < N_; k0 += 64) {
#pragma unroll
      for (int mb = 0; mb < 4; ++mb) {
        // A-frags for S: pre-cast bf16 kk rows (pure loads, no VALU)
        const unsigned short* kp = kkh + (k0 + mb * 16 + c) * D_;
        s16x8 ka0 = *(const s16x8*)(kp + q * 8);
        s16x8 ka1 = *(const s16x8*)(kp + 32 + q * 8);
        // F loads issued early (latency overlap with MFMA/exp)
        f32x4 fv[4];
#pragma unroll
        for (int md = 0; md < 4; ++md)
          fv[md] =
              *(const f32x4*)(vkh + (md * 16 + c) * N_ + k0 + mb * 16 + q * 4);

        f32x4 st[4];
#pragma unroll
        for (int nb = 0; nb < 4; ++nb) {
          f32x4 z = (f32x4){0.f, 0.f, 0.f, 0.f};
          z = mfma32(ka0, qf[nb][0], z);
          z = mfma32(ka1, qf[nb][1], z);
          st[nb] = z;
        }
        s16x4 pn[4];
#pragma unroll
        for (int nb = 0; nb < 4; ++nb) {
          float p0 = __builtin_exp2f(st[nb].x);
          float p1 = __builtin_exp2f(st[nb].y);
          float p2 = __builtin_exp2f(st[nb].z);
          float p3 = __builtin_exp2f(st[nb].w);
          lac[nb] += (p0 + p1) + (p2 + p3);
          union { unsigned u[2]; s16x4 v4; } t;
          t.u[0] = pk_bf16(p0, p1);
          t.u[1] = pk_bf16(p2, p3);
          pn[nb] = t.v4;
        }
        // PV slice: K=16 over this t-slice
#pragma unroll
        for (int md = 0; md < 4; ++md) {
          float s = vjv[md];
          union { unsigned u[2]; s16x4 v4; } t;
          t.u[0] = pk_bf16(fv[md].x * s, fv[md].y * s);
          t.u[1] = pk_bf16(fv[md].z * s, fv[md].w * s);
#pragma unroll
          for (int nb = 0; nb < 4; ++nb)
            acc[md][nb] = mfma16(t.v4, pn[nb], acc[md][nb]);
        }
      }
    }
  }

  // ---- epilogue: cross-wave tree reduce (stride 68 kills bank conflicts) --
  __shared__ float red[2][64 * 68];  // 34.8 KB
  __shared__ float lredA[2][64];
  __shared__ float lredB[64];

  float lv[4];
#pragma unroll
  for (int nb = 0; nb < 4; ++nb) {
    float v = lac[nb];
    v += __shfl_xor(v, 16);
    v += __shfl_xor(v, 32);
    lv[nb] = v;  // valid at q==0 lanes
  }

  if (wave >= 2) {
    float* dst = red[wave - 2];
#pragma unroll
    for (int mb = 0; mb < 4; ++mb)
#pragma unroll
      for (int nb = 0; nb < 4; ++nb)
        *(f32x4*)&dst[(nb * 16 + c) * 68 + mb * 16 + q * 4] = acc[mb][nb];
    if (q == 0)
#pragma unroll
      for (int nb = 0; nb < 4; ++nb) lredA[wave - 2][nb * 16 + c] = lv[nb];
  }
  __syncthreads();
  if (wave < 2) {
    const float* src = red[wave];
#pragma unroll
    for (int mb = 0; mb < 4; ++mb)
#pragma unroll
      for (int nb = 0; nb < 4; ++nb)
        acc[mb][nb] += *(const f32x4*)&src[(nb * 16 + c) * 68 + mb * 16 + q * 4];
    if (q == 0)
#pragma unroll
      for (int nb = 0; nb < 4; ++nb) lv[nb] += lredA[wave][nb * 16 + c];
  }
  __syncthreads();
  if (wave == 1) {
#pragma unroll
    for (int mb = 0; mb < 4; ++mb)
#pragma unroll
      for (int nb = 0; nb < 4; ++nb)
        *(f32x4*)&red[0][(nb * 16 + c) * 68 + mb * 16 + q * 4] = acc[mb][nb];
    if (q == 0)
#pragma unroll
      for (int nb = 0; nb < 4; ++nb) lredB[nb * 16 + c] = lv[nb];
  }
  __syncthreads();
  if (wave == 0) {
    float* out = slab + ((h * 32 + jc) * 4 + ic) * 4096;
#pragma unroll
    for (int mb = 0; mb < 4; ++mb)
#pragma unroll
      for (int nb = 0; nb < 4; ++nb) {
        f32x4 v = acc[mb][nb] +
                  *(const f32x4*)&red[0][(nb * 16 + c) * 68 + mb * 16 + q * 4];
        *(f32x4*)(out + (nb * 16 + c) * 64 + mb * 16 + q * 4) = v;
      }
    if (q == 0)
#pragma unroll
      for (int nb = 0; nb < 4; ++nb)
        lslab[(h * 32 + jc) * 256 + ic * 64 + nb * 16 + c] =
            lv[nb] + lredB[nb * 16 + c];
  }
}

// ---------------------------------------------------------------------------
// Kernel 3: reduce 32 j-chunk partials, normalize, head re-interleave.
// ---------------------------------------------------------------------------
__global__ __launch_bounds__(256) void reduce_kernel(
    const float* __restrict__ slab, const float* __restrict__ lslab,
    float* __restrict__ yn) {
  int idx = blockIdx.x * 256 + threadIdx.x;  // 131072 = 8h*4ic*64il*64d
  int h = idx >> 14;
  int r = idx & 16383;
  int ic = r >> 12;
  int il = (r >> 6) & 63;
  int d = r & 63;
  float s = 0.f, l = 0.f;
#pragma unroll 4
  for (int jc = 0; jc < 32; ++jc) {
    s += slab[(((h * 32 + jc) * 4 + ic) << 12) + il * 64 + d];
    l += lslab[(h * 32 + jc) * 256 + ic * 64 + il];
  }
  int i = ic * 64 + il;
  yn[i * C_ + h * 64 + d] = s / l;
}

// ---------------------------------------------------------------------------
// Kernel 4: out = yn[256,512] @ W_out[512,512] + b_out   (fp32, grid (8,8))
// ---------------------------------------------------------------------------
__global__ __launch_bounds__(256) void out_gemm(
    const float* __restrict__ A, const float* __restrict__ W,
    const float* __restrict__ b, float* __restrict__ out) {
  __shared__ float As[16][33];
  __shared__ float Bs[16][68];
  const int bx = blockIdx.x;
  const int by = blockIdx.y;
  const int tid = threadIdx.x;
  const int tr = (tid >> 5) * 4;
  const int tc = (tid & 31) * 2;
  float accv[4][2] = {};

  for (int k0 = 0; k0 < C_; k0 += 16) {
#pragma unroll
    for (int t = 0; t < 2; ++t) {
      int e = tid + t * 256;
      int r = e >> 4, kq = e & 15;
      As[kq][r] = A[(by * 32 + r) * C_ + k0 + kq];
    }
    {
      int br = tid >> 4, bc = (tid & 15) * 4;
      *(f32x4*)&Bs[br][bc] = *(const f32x4*)&W[(k0 + br) * C_ + bx * 64 + bc];
    }
    __syncthreads();
#pragma unroll
    for (int kq = 0; kq < 16; ++kq) {
      float a0 = As[kq][tr + 0], a1 = As[kq][tr + 1];
      float a2 = As[kq][tr + 2], a3 = As[kq][tr + 3];
      float b0 = Bs[kq][tc + 0], b1 = Bs[kq][tc + 1];
      accv[0][0] += a0 * b0; accv[0][1] += a0 * b1;
      accv[1][0] += a1 * b0; accv[1][1] += a1 * b1;
      accv[2][0] += a2 * b0; accv[2][1] += a2 * b1;
      accv[3][0] += a3 * b0; accv[3][1] += a3 * b1;
    }
    __syncthreads();
  }
#pragma unroll
  for (int rr = 0; rr < 4; ++rr)
#pragma unroll
    for (int cc = 0; cc < 2; ++cc) {
      int i = by * 32 + tr + rr;
      int col = bx * 64 + tc + cc;
      out[i * C_ + col] = accv[rr][cc] + b[col];
    }
}

// ---------------------------------------------------------------------------
extern "C" void kernel_launch(void* const* d_in, const int* in_sizes, int n_in,
                              void* d_out, int out_size, void* d_ws,
                              size_t ws_size, hipStream_t stream) {
  const float* x     = (const float*)d_in[0];
  const float* W_att = (const float*)d_in[1];
  const float* b_att = (const float*)d_in[2];
  const float* W_out = (const float*)d_in[3];
  const float* b_out = (const float*)d_in[4];

  char* ws = (char*)d_ws;
  float* slab           = (float*)(ws + 0);         // 16777216 B
  float* lslab          = (float*)(ws + 16777216);  //   262144 B
  float* qSb            = (float*)(ws + 17039360);  //   524288 B
  float* kj             = (float*)(ws + 17563648);  //   524288 B
  unsigned short* kkB   = (unsigned short*)(ws + 18087936);  // 262144 B
  float* vj             = (float*)(ws + 18350080);  //   524288 B
  float* vkT            = (float*)(ws + 18874368);  //   524288 B
  float* yn             = (float*)(ws + 19398656);  //   524288 B

  proj_kernel<<<dim3(40, 4), 256, 0, stream>>>(x, W_att, b_att, qSb, kj, kkB,
                                               vj, vkT);
  flash3_kernel<<<dim3(8, 4, 32), 256, 0, stream>>>(qSb, kj, kkB, vj, vkT,
                                                    slab, lslab);
  reduce_kernel<<<dim3(512), 256, 0, stream>>>(slab, lslab, yn);
  out_gemm<<<dim3(8, 8), 256, 0, stream>>>(yn, W_out, b_out, (float*)d_out);
}

// Round 4
// 228.616 us; speedup vs baseline: 2.9474x; 1.1115x over previous
//
#include <hip/hip_runtime.h>
#include <stdint.h>

// ---------------------------------------------------------------------------
// ThirdOrderAttention: B=1, N=256, C=512, H=8, D=64
// Flash attention over virtual L=65536 KV (K'=kj*kk, V'=vj*vk), bf16 MFMA.
// R4: aux-kernel round — proj/out_gemm retiled BM=16/BN=64/BK=32 with 640/128
// blocks (were 160/64, <1 block/CU latency-bound). flash3 frozen from R3.
// ---------------------------------------------------------------------------

typedef __attribute__((ext_vector_type(4))) float f32x4;
typedef __attribute__((ext_vector_type(4))) short s16x4;
typedef __attribute__((ext_vector_type(8))) short s16x8;

#define H_ 8
#define N_ 256
#define D_ 64
#define C_ 512
#define NC5 2560
#define SCALE_LOG2E 0.1803368801111204f  // 0.125 * log2(e): P = exp2(S')

// ----- bf16 helpers --------------------------------------------------------
__device__ __forceinline__ unsigned short f2bf_rne(float x) {
  union { float f; unsigned u; } a; a.f = x;
  unsigned r = a.u + 0x7fffu + ((a.u >> 16) & 1u);
  return (unsigned short)(r >> 16);
}

__device__ __forceinline__ unsigned pk_bf16(float a, float b) {
#if __has_builtin(__builtin_amdgcn_cvt_pk_bf16_f32)
  typedef __attribute__((ext_vector_type(2))) __bf16 bf16x2;
  union { bf16x2 v; unsigned u; } u;
  u.v = __builtin_amdgcn_cvt_pk_bf16_f32(a, b);
  return u.u;
#else
  return (unsigned)f2bf_rne(a) | ((unsigned)f2bf_rne(b) << 16);
#endif
}

// ----- MFMA wrappers -------------------------------------------------------
__device__ __forceinline__ f32x4 mfma32(s16x8 a, s16x8 b, f32x4 c) {
  return __builtin_amdgcn_mfma_f32_16x16x32_bf16(a, b, c, 0, 0, 0);
}

__device__ __forceinline__ f32x4 mfma16(s16x4 a, s16x4 b, f32x4 c) {
#if __has_builtin(__builtin_amdgcn_mfma_f32_16x16x16bf16_1k)
  return __builtin_amdgcn_mfma_f32_16x16x16bf16_1k(a, b, c, 0, 0, 0);
#else
  asm volatile("s_nop 1\n\t"
               "v_mfma_f32_16x16x16_bf16 %0, %1, %2, %0\n\t"
               "s_nop 7\n\t"
               "s_nop 2"
               : "+v"(c) : "v"(a), "v"(b));
  return c;
#endif
}

// ---------------------------------------------------------------------------
// Kernel 1: projection GEMM  p = x[256,512] @ W_att[512,2560] + b_att
// BM=16, BN=64, BK=32; 256 threads; 1x4 micro-tile. Grid (40, 16) = 640 blks.
// 64-col tile maps to exactly one part (320 = 5*64) -> uniform epilogue.
// ---------------------------------------------------------------------------
__global__ __launch_bounds__(256) void proj_kernel(
    const float* __restrict__ x, const float* __restrict__ W,
    const float* __restrict__ b,
    float* __restrict__ qS, float* __restrict__ kj,
    unsigned short* __restrict__ kkB, float* __restrict__ vj,
    float* __restrict__ vkT) {
  __shared__ float As[32][17];
  __shared__ float Bs[32][68];
  const int bx = blockIdx.x;  // 40 col tiles of 64
  const int by = blockIdx.y;  // 16 row tiles of 16
  const int tid = threadIdx.x;
  const int m = tid >> 4;        // 0..15 output row
  const int c4 = (tid & 15) * 4; // output col group
  float acc0 = 0.f, acc1 = 0.f, acc2 = 0.f, acc3 = 0.f;

  const int lk = tid & 31;   // A-load k
  const int lm = tid >> 5;   // A-load m (0..7), +8 second half
  const int bk = tid >> 4;   // B-load k (0..15), +16 second half

  for (int k0 = 0; k0 < C_; k0 += 32) {
    As[lk][lm] = x[(by * 16 + lm) * C_ + k0 + lk];
    As[lk][lm + 8] = x[(by * 16 + lm + 8) * C_ + k0 + lk];
    *(f32x4*)&Bs[bk][c4] = *(const f32x4*)&W[(k0 + bk) * NC5 + bx * 64 + c4];
    *(f32x4*)&Bs[bk + 16][c4] =
        *(const f32x4*)&W[(k0 + bk + 16) * NC5 + bx * 64 + c4];
    __syncthreads();
#pragma unroll
    for (int kq = 0; kq < 32; ++kq) {
      float a = As[kq][m];
      f32x4 bv = *(const f32x4*)&Bs[kq][c4];
      acc0 += a * bv.x; acc1 += a * bv.y; acc2 += a * bv.z; acc3 += a * bv.w;
    }
    __syncthreads();
  }

  const int i = by * 16 + m;
  const int col0 = bx * 64 + c4;
  const int h = (bx * 64) / 320;
  const int part = ((bx * 64) % 320) >> 6;
  const int d0 = c4;
  float v0 = acc0 + b[col0 + 0];
  float v1 = acc1 + b[col0 + 1];
  float v2 = acc2 + b[col0 + 2];
  float v3 = acc3 + b[col0 + 3];
  const int idx = (h * N_ + i) * D_ + d0;
  if (part == 0) {
    f32x4 o = {v0 * SCALE_LOG2E, v1 * SCALE_LOG2E, v2 * SCALE_LOG2E,
               v3 * SCALE_LOG2E};
    *(f32x4*)(qS + idx) = o;
  } else if (part == 1) {
    f32x4 o = {v0, v1, v2, v3};
    *(f32x4*)(kj + idx) = o;
  } else if (part == 2) {
    union { unsigned u[2]; s16x4 v4; } t;
    t.u[0] = pk_bf16(v0, v1);
    t.u[1] = pk_bf16(v2, v3);
    *(s16x4*)(kkB + idx) = t.v4;
  } else if (part == 3) {
    f32x4 o = {v0, v1, v2, v3};
    *(f32x4*)(vj + idx) = o;
  } else {
    vkT[(h * D_ + d0 + 0) * N_ + i] = v0;
    vkT[(h * D_ + d0 + 1) * N_ + i] = v1;
    vkT[(h * D_ + d0 + 2) * N_ + i] = v2;
    vkT[(h * D_ + d0 + 3) * N_ + i] = v3;
  }
}

// ---------------------------------------------------------------------------
// Kernel 2: fused third-order flash attention (atomic-free). FROZEN from R3.
// Grid (8 h, 4 ic of 64 i, 32 jc of 8 j). Block 256 = 4 waves; each wave owns
// 2 j's, 64 i, all 256 k. Per (j, k0-tile of 64):
//   per 16-t slice mb: S^T = kk_bf16 . q~   (q~ = bf16(qS * kj), per-j)
//   P = exp2(S'); S^T C-layout == mfma16 B-layout -> immediate PV slice:
//   Y^T[d,i] += F[d,t16] @ P^T  (F = bf16(vj*vkT) built in-regs)
// Epilogue: LDS tree reduce over 4 waves, one 16 KB slab write per block.
// ---------------------------------------------------------------------------
__global__ __launch_bounds__(256, 2) void flash3_kernel(
    const float* __restrict__ qS,           // [H][N][D] f32, pre-scaled
    const float* __restrict__ kjF,          // [H][N][D] f32
    const unsigned short* __restrict__ kkB, // [H][N][D] bf16
    const float* __restrict__ vjF,          // [H][N][D] f32
    const float* __restrict__ vkT,          // [H][D][N] f32
    float* __restrict__ slab,               // [H][32][4][64][64]
    float* __restrict__ lslab) {            // [H][32][256]
  const int h = blockIdx.x;
  const int ic = blockIdx.y;
  const int jc = blockIdx.z;
  const int wave = threadIdx.x >> 6;
  const int lane = threadIdx.x & 63;
  const int q = lane >> 4;
  const int c = lane & 15;
  const int i0 = ic * 64;

  const float* qh = qS + h * (N_ * D_);
  const float* kjh = kjF + h * (N_ * D_);
  const unsigned short* kkh = kkB + h * (N_ * D_);
  const float* vjh = vjF + h * (N_ * D_);
  const float* vkh = vkT + h * (D_ * N_);

  f32x4 acc[4][4];  // Y^T tiles: [mb_d][nb over i]
#pragma unroll
  for (int mb = 0; mb < 4; ++mb)
#pragma unroll
    for (int nb = 0; nb < 4; ++nb) acc[mb][nb] = (f32x4){0.f, 0.f, 0.f, 0.f};
  float lac[4] = {0.f, 0.f, 0.f, 0.f};

  for (int jj = 0; jj < 2; ++jj) {
    const int j = jc * 8 + wave * 2 + jj;
    const f32x4 kj0a = *(const f32x4*)(kjh + j * D_ + q * 8);
    const f32x4 kj0b = *(const f32x4*)(kjh + j * D_ + q * 8 + 4);
    const f32x4 kj1a = *(const f32x4*)(kjh + j * D_ + 32 + q * 8);
    const f32x4 kj1b = *(const f32x4*)(kjh + j * D_ + 32 + q * 8 + 4);
    float vjv[4];
#pragma unroll
    for (int mb = 0; mb < 4; ++mb) vjv[mb] = vjh[j * D_ + mb * 16 + c];

    // q~ B-fragments: B[k=d][n=i], q~ = bf16(qS * kj)
    s16x8 qf[4][2];
#pragma unroll
    for (int nb = 0; nb < 4; ++nb) {
      const float* qp = qh + (i0 + nb * 16 + c) * D_;
      f32x4 a0 = *(const f32x4*)(qp + q * 8);
      f32x4 a1 = *(const f32x4*)(qp + q * 8 + 4);
      f32x4 b0 = *(const f32x4*)(qp + 32 + q * 8);
      f32x4 b1 = *(const f32x4*)(qp + 32 + q * 8 + 4);
      union { unsigned u[4]; s16x8 v; } t0, t1;
      t0.u[0] = pk_bf16(a0.x * kj0a.x, a0.y * kj0a.y);
      t0.u[1] = pk_bf16(a0.z * kj0a.z, a0.w * kj0a.w);
      t0.u[2] = pk_bf16(a1.x * kj0b.x, a1.y * kj0b.y);
      t0.u[3] = pk_bf16(a1.z * kj0b.z, a1.w * kj0b.w);
      t1.u[0] = pk_bf16(b0.x * kj1a.x, b0.y * kj1a.y);
      t1.u[1] = pk_bf16(b0.z * kj1a.z, b0.w * kj1a.w);
      t1.u[2] = pk_bf16(b1.x * kj1b.x, b1.y * kj1b.y);
      t1.u[3] = pk_bf16(b1.z * kj1b.z, b1.w * kj1b.w);
      qf[nb][0] = t0.v;
      qf[nb][1] = t1.v;
    }

    for (int k0 = 0; k0 < N_; k0 += 64) {
#pragma unroll
      for (int mb = 0; mb < 4; ++mb) {
        // A-frags for S: pre-cast bf16 kk rows (pure loads, no VALU)
        const unsigned short* kp = kkh + (k0 + mb * 16 + c) * D_;
        s16x8 ka0 = *(const s16x8*)(kp + q * 8);
        s16x8 ka1 = *(const s16x8*)(kp + 32 + q * 8);
        // F loads issued early (latency overlap with MFMA/exp)
        f32x4 fv[4];
#pragma unroll
        for (int md = 0; md < 4; ++md)
          fv[md] =
              *(const f32x4*)(vkh + (md * 16 + c) * N_ + k0 + mb * 16 + q * 4);

        f32x4 st[4];
#pragma unroll
        for (int nb = 0; nb < 4; ++nb) {
          f32x4 z = (f32x4){0.f, 0.f, 0.f, 0.f};
          z = mfma32(ka0, qf[nb][0], z);
          z = mfma32(ka1, qf[nb][1], z);
          st[nb] = z;
        }
        s16x4 pn[4];
#pragma unroll
        for (int nb = 0; nb < 4; ++nb) {
          float p0 = __builtin_exp2f(st[nb].x);
          float p1 = __builtin_exp2f(st[nb].y);
          float p2 = __builtin_exp2f(st[nb].z);
          float p3 = __builtin_exp2f(st[nb].w);
          lac[nb] += (p0 + p1) + (p2 + p3);
          union { unsigned u[2]; s16x4 v4; } t;
          t.u[0] = pk_bf16(p0, p1);
          t.u[1] = pk_bf16(p2, p3);
          pn[nb] = t.v4;
        }
        // PV slice: K=16 over this t-slice
#pragma unroll
        for (int md = 0; md < 4; ++md) {
          float s = vjv[md];
          union { unsigned u[2]; s16x4 v4; } t;
          t.u[0] = pk_bf16(fv[md].x * s, fv[md].y * s);
          t.u[1] = pk_bf16(fv[md].z * s, fv[md].w * s);
#pragma unroll
          for (int nb = 0; nb < 4; ++nb)
            acc[md][nb] = mfma16(t.v4, pn[nb], acc[md][nb]);
        }
      }
    }
  }

  // ---- epilogue: cross-wave tree reduce (stride 68 kills bank conflicts) --
  __shared__ float red[2][64 * 68];  // 34.8 KB
  __shared__ float lredA[2][64];
  __shared__ float lredB[64];

  float lv[4];
#pragma unroll
  for (int nb = 0; nb < 4; ++nb) {
    float v = lac[nb];
    v += __shfl_xor(v, 16);
    v += __shfl_xor(v, 32);
    lv[nb] = v;  // valid at q==0 lanes
  }

  if (wave >= 2) {
    float* dst = red[wave - 2];
#pragma unroll
    for (int mb = 0; mb < 4; ++mb)
#pragma unroll
      for (int nb = 0; nb < 4; ++nb)
        *(f32x4*)&dst[(nb * 16 + c) * 68 + mb * 16 + q * 4] = acc[mb][nb];
    if (q == 0)
#pragma unroll
      for (int nb = 0; nb < 4; ++nb) lredA[wave - 2][nb * 16 + c] = lv[nb];
  }
  __syncthreads();
  if (wave < 2) {
    const float* src = red[wave];
#pragma unroll
    for (int mb = 0; mb < 4; ++mb)
#pragma unroll
      for (int nb = 0; nb < 4; ++nb)
        acc[mb][nb] += *(const f32x4*)&src[(nb * 16 + c) * 68 + mb * 16 + q * 4];
    if (q == 0)
#pragma unroll
      for (int nb = 0; nb < 4; ++nb) lv[nb] += lredA[wave][nb * 16 + c];
  }
  __syncthreads();
  if (wave == 1) {
#pragma unroll
    for (int mb = 0; mb < 4; ++mb)
#pragma unroll
      for (int nb = 0; nb < 4; ++nb)
        *(f32x4*)&red[0][(nb * 16 + c) * 68 + mb * 16 + q * 4] = acc[mb][nb];
    if (q == 0)
#pragma unroll
      for (int nb = 0; nb < 4; ++nb) lredB[nb * 16 + c] = lv[nb];
  }
  __syncthreads();
  if (wave == 0) {
    float* out = slab + ((h * 32 + jc) * 4 + ic) * 4096;
#pragma unroll
    for (int mb = 0; mb < 4; ++mb)
#pragma unroll
      for (int nb = 0; nb < 4; ++nb) {
        f32x4 v = acc[mb][nb] +
                  *(const f32x4*)&red[0][(nb * 16 + c) * 68 + mb * 16 + q * 4];
        *(f32x4*)(out + (nb * 16 + c) * 64 + mb * 16 + q * 4) = v;
      }
    if (q == 0)
#pragma unroll
      for (int nb = 0; nb < 4; ++nb)
        lslab[(h * 32 + jc) * 256 + ic * 64 + nb * 16 + c] =
            lv[nb] + lredB[nb * 16 + c];
  }
}

// ---------------------------------------------------------------------------
// Kernel 3: reduce 32 j-chunk partials, normalize, head re-interleave.
// ---------------------------------------------------------------------------
__global__ __launch_bounds__(256) void reduce_kernel(
    const float* __restrict__ slab, const float* __restrict__ lslab,
    float* __restrict__ yn) {
  int idx = blockIdx.x * 256 + threadIdx.x;  // 131072 = 8h*4ic*64il*64d
  int h = idx >> 14;
  int r = idx & 16383;
  int ic = r >> 12;
  int il = (r >> 6) & 63;
  int d = r & 63;
  float s = 0.f, l = 0.f;
#pragma unroll 4
  for (int jc = 0; jc < 32; ++jc) {
    s += slab[(((h * 32 + jc) * 4 + ic) << 12) + il * 64 + d];
    l += lslab[(h * 32 + jc) * 256 + ic * 64 + il];
  }
  int i = ic * 64 + il;
  yn[i * C_ + h * 64 + d] = s / l;
}

// ---------------------------------------------------------------------------
// Kernel 4: out = yn[256,512] @ W_out[512,512] + b_out
// BM=16, BN=64, BK=32; grid (8,16) = 128 blocks.
// ---------------------------------------------------------------------------
__global__ __launch_bounds__(256) void out_gemm(
    const float* __restrict__ A, const float* __restrict__ W,
    const float* __restrict__ b, float* __restrict__ out) {
  __shared__ float As[32][17];
  __shared__ float Bs[32][68];
  const int bx = blockIdx.x;  // 8 col tiles of 64
  const int by = blockIdx.y;  // 16 row tiles of 16
  const int tid = threadIdx.x;
  const int m = tid >> 4;
  const int c4 = (tid & 15) * 4;
  float acc0 = 0.f, acc1 = 0.f, acc2 = 0.f, acc3 = 0.f;

  const int lk = tid & 31;
  const int lm = tid >> 5;
  const int bk = tid >> 4;

  for (int k0 = 0; k0 < C_; k0 += 32) {
    As[lk][lm] = A[(by * 16 + lm) * C_ + k0 + lk];
    As[lk][lm + 8] = A[(by * 16 + lm + 8) * C_ + k0 + lk];
    *(f32x4*)&Bs[bk][c4] = *(const f32x4*)&W[(k0 + bk) * C_ + bx * 64 + c4];
    *(f32x4*)&Bs[bk + 16][c4] =
        *(const f32x4*)&W[(k0 + bk + 16) * C_ + bx * 64 + c4];
    __syncthreads();
#pragma unroll
    for (int kq = 0; kq < 32; ++kq) {
      float a = As[kq][m];
      f32x4 bv = *(const f32x4*)&Bs[kq][c4];
      acc0 += a * bv.x; acc1 += a * bv.y; acc2 += a * bv.z; acc3 += a * bv.w;
    }
    __syncthreads();
  }

  const int i = by * 16 + m;
  const int col = bx * 64 + c4;
  f32x4 o = {acc0 + b[col + 0], acc1 + b[col + 1], acc2 + b[col + 2],
             acc3 + b[col + 3]};
  *(f32x4*)(out + i * C_ + col) = o;
}

// ---------------------------------------------------------------------------
extern "C" void kernel_launch(void* const* d_in, const int* in_sizes, int n_in,
                              void* d_out, int out_size, void* d_ws,
                              size_t ws_size, hipStream_t stream) {
  const float* x     = (const float*)d_in[0];
  const float* W_att = (const float*)d_in[1];
  const float* b_att = (const float*)d_in[2];
  const float* W_out = (const float*)d_in[3];
  const float* b_out = (const float*)d_in[4];

  char* ws = (char*)d_ws;
  float* slab           = (float*)(ws + 0);         // 16777216 B
  float* lslab          = (float*)(ws + 16777216);  //   262144 B
  float* qSb            = (float*)(ws + 17039360);  //   524288 B
  float* kj             = (float*)(ws + 17563648);  //   524288 B
  unsigned short* kkB   = (unsigned short*)(ws + 18087936);  // 262144 B
  float* vj             = (float*)(ws + 18350080);  //   524288 B
  float* vkT            = (float*)(ws + 18874368);  //   524288 B
  float* yn             = (float*)(ws + 19398656);  //   524288 B

  proj_kernel<<<dim3(40, 16), 256, 0, stream>>>(x, W_att, b_att, qSb, kj, kkB,
                                                vj, vkT);
  flash3_kernel<<<dim3(8, 4, 32), 256, 0, stream>>>(qSb, kj, kkB, vj, vkT,
                                                    slab, lslab);
  reduce_kernel<<<dim3(512), 256, 0, stream>>>(slab, lslab, yn);
  out_gemm<<<dim3(8, 16), 256, 0, stream>>>(yn, W_out, b_out, (float*)d_out);
}